// Round 1
// baseline (308.440 us; speedup 1.0000x reference)
//
#include <hip/hip_runtime.h>

// WideAndDeep fused inference, fp32.
// Layout: 512 blocks x 512 threads, 32 samples per block.
// LDS: xs[32][128] (16KB, reused as h2) + h1[32][256] (32KB, reused as h3)
//      + wbuf[4096] (16KB weight staging chunk) = exactly 64KB -> 2 blocks/CU.

#define NT 512
#define TS 32

constexpr int NUM_USERS = 500000;
// 1/sqrt(1 + 1e-5): eval-mode BN with running_mean=0, running_var=1
constexpr float BN_INV = 0.9999950000374997f;

struct __align__(16) Smem {
    float xs[TS * 128];   // input x; later reused as h2 (32x128)
    float h1[TS * 256];   // h1; later reused as h3 (32x64)
    float wbuf[4096];     // weight staging chunk (16KB)
};

#define FMA4(xk, wv, a)                      \
    do {                                     \
        (a).x = fmaf((xk), (wv).x, (a).x);   \
        (a).y = fmaf((xk), (wv).y, (a).y);   \
        (a).z = fmaf((xk), (wv).z, (a).z);   \
        (a).w = fmaf((xk), (wv).w, (a).w);   \
    } while (0)

// One Linear(K,N) + ReLU + eval-BN layer over a 32-sample tile held in LDS.
// Thread t computes S=N/64 samples x 4 features; weights staged via wbuf.
template <int K, int N>
__device__ __forceinline__ void mlp_layer(
    const float* __restrict__ w, const float* __restrict__ bias,
    const float* __restrict__ gamma, const float* __restrict__ beta,
    const float* in_lds, float* out_lds, float* wbuf, int t)
{
    constexpr int JG = N / 4;     // feature groups of 4
    constexpr int S  = N / 64;    // samples per thread (TS*JG/NT)
    constexpr int CK = 4096 / N;  // k-rows per staged chunk

    const int j0 = (t % JG) * 4;
    const int s0 = (t / JG) * S;

    float4 acc[S];
#pragma unroll
    for (int s = 0; s < S; ++s) acc[s] = make_float4(0.f, 0.f, 0.f, 0.f);

    for (int kc = 0; kc < K; kc += CK) {
        __syncthreads();  // prior readers of wbuf / writers of in_lds done
        // stage CK*N = 4096 floats, coalesced: 1024 float4 / 512 threads
        {
            const float4* src = (const float4*)(w + kc * N);
            float4* dst = (float4*)wbuf;
            dst[t]       = src[t];
            dst[t + 512] = src[t + 512];
        }
        __syncthreads();

#pragma unroll
        for (int k4 = 0; k4 < CK; k4 += 4) {
            float4 xv[S];
#pragma unroll
            for (int s = 0; s < S; ++s)
                xv[s] = *(const float4*)&in_lds[(s0 + s) * K + kc + k4];
#pragma unroll
            for (int kk = 0; kk < 4; ++kk) {
                float4 wv = *(const float4*)&wbuf[(k4 + kk) * N + j0];
#pragma unroll
                for (int s = 0; s < S; ++s) {
                    float xk = (kk == 0) ? xv[s].x
                             : (kk == 1) ? xv[s].y
                             : (kk == 2) ? xv[s].z
                                         : xv[s].w;
                    FMA4(xk, wv, acc[s]);
                }
            }
        }
    }

    // epilogue: bias -> relu -> BN(eval), write to out LDS
    const float4 bv = *(const float4*)&bias[j0];
    const float4 gv = *(const float4*)&gamma[j0];
    const float4 ev = *(const float4*)&beta[j0];
#pragma unroll
    for (int s = 0; s < S; ++s) {
        float4 o;
        o.x = fmaxf(acc[s].x + bv.x, 0.f) * (gv.x * BN_INV) + ev.x;
        o.y = fmaxf(acc[s].y + bv.y, 0.f) * (gv.y * BN_INV) + ev.y;
        o.z = fmaxf(acc[s].z + bv.z, 0.f) * (gv.z * BN_INV) + ev.z;
        o.w = fmaxf(acc[s].w + bv.w, 0.f) * (gv.w * BN_INV) + ev.w;
        *(float4*)&out_lds[(s0 + s) * N + j0] = o;
    }
    // no trailing sync: next layer's first __syncthreads covers these writes
}

__global__ __launch_bounds__(NT) void wd_kernel(
    const int* __restrict__ user_ids, const int* __restrict__ item_ids,
    const float* __restrict__ wide_w, const float* __restrict__ wide_b,
    const float* __restrict__ user_table, const float* __restrict__ item_table,
    const float* __restrict__ w1, const float* __restrict__ b1,
    const float* __restrict__ g1, const float* __restrict__ be1,
    const float* __restrict__ w2, const float* __restrict__ b2,
    const float* __restrict__ g2, const float* __restrict__ be2,
    const float* __restrict__ w3, const float* __restrict__ b3,
    const float* __restrict__ g3, const float* __restrict__ be3,
    const float* __restrict__ w4, const float* __restrict__ b4,
    float* __restrict__ out)
{
    __shared__ Smem sm;
    const int t = threadIdx.x;
    const int sbase = blockIdx.x * TS;

    // ---- gather: xs[s][0:64] = user row, xs[s][64:128] = item row ----
    {
        const int s = t >> 4;         // 0..31
        const int p = t & 15;         // 0..15  (16 float4 per 64-float half)
        const int uid = user_ids[sbase + s];
        const int iid = item_ids[sbase + s];
        ((float4*)&sm.xs[s * 128])[p] =
            ((const float4*)(user_table + (long)uid * 64))[p];
        ((float4*)&sm.xs[s * 128])[16 + p] =
            ((const float4*)(item_table + (long)iid * 64))[p];
    }

    // ---- wide path: computed by the thread that will write out[s] ----
    float widev = 0.0f;
    if (t < TS * 8 && (t & 7) == 0) {
        const int s = t >> 3;
        const int uid = user_ids[sbase + s];
        const int iid = item_ids[sbase + s];
        widev = wide_w[uid] + wide_w[NUM_USERS + iid] + wide_b[0];
    }

    // ---- deep MLP (syncs handled inside; first sync covers gather) ----
    mlp_layer<128, 256>(w1, b1, g1, be1, sm.xs, sm.h1, sm.wbuf, t);  // x  -> h1
    mlp_layer<256, 128>(w2, b2, g2, be2, sm.h1, sm.xs, sm.wbuf, t);  // h1 -> h2 (in xs)
    mlp_layer<128, 64 >(w3, b3, g3, be3, sm.xs, sm.h1, sm.wbuf, t);  // h2 -> h3 (in h1)
    __syncthreads();

    // ---- layer 4: dot(h3[s], w4) + b4, 8 threads per sample ----
    if (t < TS * 8) {
        const int s = t >> 3;
        const int g = t & 7;
        const float* h = &sm.h1[s * 64 + g * 8];
        const float4 ha = *(const float4*)(h);
        const float4 hb = *(const float4*)(h + 4);
        const float4 wa = *(const float4*)(w4 + g * 8);
        const float4 wb = *(const float4*)(w4 + g * 8 + 4);
        float p = ha.x * wa.x + ha.y * wa.y + ha.z * wa.z + ha.w * wa.w
                + hb.x * wb.x + hb.y * wb.y + hb.z * wb.z + hb.w * wb.w;
        p += __shfl_down(p, 4);
        p += __shfl_down(p, 2);
        p += __shfl_down(p, 1);
        if (g == 0) out[sbase + s] = widev + p + b4[0];
    }
}

extern "C" void kernel_launch(void* const* d_in, const int* in_sizes, int n_in,
                              void* d_out, int out_size, void* d_ws, size_t ws_size,
                              hipStream_t stream) {
    (void)in_sizes; (void)n_in; (void)d_ws; (void)ws_size;
    const int*   user_ids   = (const int*)d_in[0];
    const int*   item_ids   = (const int*)d_in[1];
    const float* wide_w     = (const float*)d_in[2];
    const float* wide_b     = (const float*)d_in[3];
    const float* user_table = (const float*)d_in[4];
    const float* item_table = (const float*)d_in[5];
    const float* w1 = (const float*)d_in[6];
    const float* b1 = (const float*)d_in[7];
    const float* g1 = (const float*)d_in[8];
    const float* be1 = (const float*)d_in[9];
    const float* w2 = (const float*)d_in[10];
    const float* b2 = (const float*)d_in[11];
    const float* g2 = (const float*)d_in[12];
    const float* be2 = (const float*)d_in[13];
    const float* w3 = (const float*)d_in[14];
    const float* b3 = (const float*)d_in[15];
    const float* g3 = (const float*)d_in[16];
    const float* be3 = (const float*)d_in[17];
    const float* w4 = (const float*)d_in[18];
    const float* b4 = (const float*)d_in[19];
    float* out = (float*)d_out;

    const int grid = 16384 / TS;  // 512 blocks
    wd_kernel<<<grid, NT, 0, stream>>>(
        user_ids, item_ids, wide_w, wide_b, user_table, item_table,
        w1, b1, g1, be1, w2, b2, g2, be2, w3, b3, g3, be3, w4, b4, out);
}